// Round 1
// baseline (70.644 us; speedup 1.0000x reference)
//
#include <hip/hip_runtime.h>

#define N_SLOTS 65536
#define DIM 128
#define B_SZ 4096
#define K_TOP 8
#define UPDATE_RATE 0.1f
#define MOMENTUM 0.9f
#define GATE_THRESH 0.01f

// ---------------------------------------------------------------------------
// Kernel 1: scatter-add gate weights into per-slot counts (ws, 65536 floats).
// One thread per (write a, top-k k) pair: 32768 threads.
// ---------------------------------------------------------------------------
__global__ void mw_counts_kernel(const float* __restrict__ gate,
                                 const int* __restrict__ top_idx,
                                 float* __restrict__ counts) {
    int t = blockIdx.x * blockDim.x + threadIdx.x;
    if (t >= B_SZ * K_TOP) return;
    int a = t >> 3;                       // t / K_TOP
    float g = gate[a];
    float w = (g > GATE_THRESH) ? g * UPDATE_RATE : 0.0f;
    if (w != 0.0f) {
        atomicAdd(&counts[top_idx[t]], w);
    }
}

// ---------------------------------------------------------------------------
// Kernel 2: out = memory + MOMENTUM * momentum   (both keys and values).
// Pure streaming: 134 MB read + 67 MB write, float4 vectorized.
// ---------------------------------------------------------------------------
__global__ void mw_base_kernel(const float4* __restrict__ mk,
                               const float4* __restrict__ mv,
                               const float4* __restrict__ km,
                               const float4* __restrict__ vm,
                               float4* __restrict__ outk,
                               float4* __restrict__ outv,
                               int n4) {
    int i = blockIdx.x * blockDim.x + threadIdx.x;
    if (i >= n4) return;
    float4 a = mk[i];
    float4 b = km[i];
    float4 r;
    r.x = a.x + MOMENTUM * b.x;
    r.y = a.y + MOMENTUM * b.y;
    r.z = a.z + MOMENTUM * b.z;
    r.w = a.w + MOMENTUM * b.w;
    outk[i] = r;
    a = mv[i];
    b = vm[i];
    r.x = a.x + MOMENTUM * b.x;
    r.y = a.y + MOMENTUM * b.y;
    r.z = a.z + MOMENTUM * b.z;
    r.w = a.w + MOMENTUM * b.w;
    outv[i] = r;
}

// ---------------------------------------------------------------------------
// Kernel 3: scatter the normalized update into the output.
// One 256-thread block per (a,k) pair. Lanes 0..127 handle the key row,
// lanes 128..255 the value row. Coefficient (1-MOMENTUM)*w/denom folds the
// count normalization and the momentum mix into a single scale, so the
// division by denom (finalized by kernel 1) happens before the scatter.
// ---------------------------------------------------------------------------
__global__ void mw_scatter_kernel(const float* __restrict__ q,
                                  const float* __restrict__ v,
                                  const float* __restrict__ gate,
                                  const int* __restrict__ top_idx,
                                  const float* __restrict__ counts,
                                  float* __restrict__ outk,
                                  float* __restrict__ outv) {
    int pair = blockIdx.x;                // 0 .. B*K-1
    int t = threadIdx.x;                  // 0 .. 255
    int a = pair >> 3;                    // pair / K_TOP
    float g = gate[a];
    float w = (g > GATE_THRESH) ? g * UPDATE_RATE : 0.0f;
    if (w == 0.0f) return;                // block-uniform: whole block exits
    int s = top_idx[pair];
    float cnt = counts[s];
    float denom = (cnt > 0.0f) ? cnt : 1.0f;
    float c = (1.0f - MOMENTUM) * w / denom;
    int d = t & (DIM - 1);
    if (t < DIM) {
        atomicAdd(&outk[s * DIM + d], c * q[a * DIM + d]);
    } else {
        atomicAdd(&outv[s * DIM + d], c * v[a * DIM + d]);
    }
}

extern "C" void kernel_launch(void* const* d_in, const int* in_sizes, int n_in,
                              void* d_out, int out_size, void* d_ws, size_t ws_size,
                              hipStream_t stream) {
    const float* memory_keys   = (const float*)d_in[0];
    const float* memory_values = (const float*)d_in[1];
    const float* write_query   = (const float*)d_in[2];
    const float* write_value   = (const float*)d_in[3];
    const float* gate_weights  = (const float*)d_in[4];
    const int*   top_indices   = (const int*)d_in[5];
    const float* key_momentum  = (const float*)d_in[6];
    const float* value_momentum= (const float*)d_in[7];

    float* out  = (float*)d_out;
    float* outk = out;
    float* outv = out + (size_t)N_SLOTS * DIM;

    float* counts = (float*)d_ws;         // 65536 floats = 256 KB

    // 0) zero the counts accumulator (deterministic per call)
    hipMemsetAsync(counts, 0, N_SLOTS * sizeof(float), stream);

    // 1) accumulate per-slot gate-weight counts
    {
        int total = B_SZ * K_TOP;         // 32768
        int block = 256;
        int grid = (total + block - 1) / block;
        mw_counts_kernel<<<grid, block, 0, stream>>>(gate_weights, top_indices, counts);
    }

    // 2) out = memory + 0.9 * momentum  (streaming, float4)
    {
        int n4 = N_SLOTS * DIM / 4;       // 2,097,152
        int block = 256;
        int grid = (n4 + block - 1) / block;
        mw_base_kernel<<<grid, block, 0, stream>>>(
            (const float4*)memory_keys, (const float4*)memory_values,
            (const float4*)key_momentum, (const float4*)value_momentum,
            (float4*)outk, (float4*)outv, n4);
    }

    // 3) scatter normalized updates into the output
    {
        int grid = B_SZ * K_TOP;          // 32768 blocks
        mw_scatter_kernel<<<grid, 256, 0, stream>>>(
            write_query, write_value, gate_weights, top_indices, counts,
            outk, outv);
    }
}